// Round 5
// baseline (276.596 us; speedup 1.0000x reference)
//
#include <hip/hip_runtime.h>
#include <hip/hip_bf16.h>

#define N_NODES 100000
#define N_EDGES 1600000
#define Y_ELEMS (16 * N_NODES * 16)            // Y[n][k][f]
#define Y_BYTES ((size_t)Y_ELEMS * 2)          // 51.2 MB bf16

__global__ __launch_bounds__(256) void zero_out_kernel(float4* __restrict__ out, int n4) {
    int i = blockIdx.x * 256 + threadIdx.x;
    if (i < n4) out[i] = make_float4(0.f, 0.f, 0.f, 0.f);
}

__device__ __forceinline__ unsigned short f2bf(float f) {
    __hip_bfloat16 h = __float2bfloat16(f);
    return *(unsigned short*)&h;
}
__device__ __forceinline__ float bf_lo(unsigned int u) { return __uint_as_float(u << 16); }
__device__ __forceinline__ float bf_hi(unsigned int u) { return __uint_as_float(u & 0xffff0000u); }

// Stage 1: Y[n][k][f] (bf16) = sum_i x[n][i] * W[k][i][f]
// 16384 waves (4096 blocks), <=7 nodes per wave: R4's 4096-wave version was
// latency-bound (~48us) on the per-node load->compute->store chain; more TLP
// hides it. W column per lane loaded once (4KB/wave, L2-served).
__global__ __launch_bounds__(256) void stage1_xw(
    const float* __restrict__ x,       // [N_NODES,16]
    const float* __restrict__ w,       // [16][16][16] = [k][i][f]
    unsigned short* __restrict__ Y)    // [N_NODES][16][16] bf16
{
    const int lane = threadIdx.x & 63;
    const int k  = lane >> 2;          // 0..15
    const int fq = lane & 3;           // 0..3
    const int gwave  = blockIdx.x * 4 + (threadIdx.x >> 6);
    const int nwaves = gridDim.x * 4;  // 16384

    float4 wr[16];
#pragma unroll
    for (int i = 0; i < 16; ++i)
        wr[i] = *(const float4*)(w + k * 256 + i * 16 + fq * 4);

    for (int n = gwave; n < N_NODES; n += nwaves) {
        const float4* xr = (const float4*)(x + (size_t)n * 16);
        float xs[16];
#pragma unroll
        for (int q = 0; q < 4; ++q) {
            float4 t4 = xr[q];
            xs[4*q+0] = t4.x; xs[4*q+1] = t4.y; xs[4*q+2] = t4.z; xs[4*q+3] = t4.w;
        }
        float4 acc = make_float4(0.f, 0.f, 0.f, 0.f);
#pragma unroll
        for (int i = 0; i < 16; ++i) {
            acc.x += xs[i] * wr[i].x; acc.y += xs[i] * wr[i].y;
            acc.z += xs[i] * wr[i].z; acc.w += xs[i] * wr[i].w;
        }
        ushort4 o;
        o.x = f2bf(acc.x); o.y = f2bf(acc.y); o.z = f2bf(acc.z); o.w = f2bf(acc.w);
        *(ushort4*)(Y + (size_t)n * 256 + k * 16 + fq * 4) = o;
    }
}

// Stage 2: 8 lanes per edge; lane l handles features 2l, 2l+1 via one bf16x2
// (uint) load per cell. Same Y sectors as R4 (32B/cell, 2 lines/edge), but
// per-edge memory lane-slots drop 128->72 and basis math is computed 8x not
// 16x. Scatter stays fully coalesced: 16 contiguous floats per edge.
__global__ __launch_bounds__(256) void stage2_fanout8(
    const int*   __restrict__ edge_index,  // [2, N_EDGES]
    const float* __restrict__ edge_attr,   // [N_EDGES, 2]
    const unsigned short* __restrict__ Y,  // [N_NODES][16][16] bf16
    float*       __restrict__ out)         // [N_NODES,16], pre-zeroed
{
    const int g = blockIdx.x * 256 + threadIdx.x;
    const int e = g >> 3;            // edge index (grid sized exactly)
    const int l = g & 7;             // feature pair: f = 2l, 2l+1

    const int row = edge_index[e];
    const int col = edge_index[N_EDGES + e];
    const float2 attr = ((const float2*)edge_attr)[e];

    float fu = (attr.x + 1.0f) * 1.5f;
    int iu = (int)fu; iu = iu < 0 ? 0 : (iu > 2 ? 2 : iu);
    const float wu1 = fu - (float)iu;
    const float wu0 = 1.0f - wu1;

    float fv = (attr.y + 1.0f) * 1.5f;
    int iv = (int)fv; iv = iv < 0 ? 0 : (iv > 2 ? 2 : iv);
    const float wv1 = fv - (float)iv;
    const float wv0 = 1.0f - wv1;

    const float t00 = wu0 * wv0, t01 = wu0 * wv1;
    const float t10 = wu1 * wv0, t11 = wu1 * wv1;
    const int k0 = iu * 4 + iv;

    // uint view of Y row: uint index = k*8 + l  (covers features 2l,2l+1)
    const unsigned int* yb = (const unsigned int*)(Y + (size_t)col * 256) + l;
    const unsigned int u00 = yb[(k0)     * 8];
    const unsigned int u01 = yb[(k0 + 1) * 8];
    const unsigned int u10 = yb[(k0 + 4) * 8];
    const unsigned int u11 = yb[(k0 + 5) * 8];

    const float m0 = t00 * bf_lo(u00) + t01 * bf_lo(u01) +
                     t10 * bf_lo(u10) + t11 * bf_lo(u11);
    const float m1 = t00 * bf_hi(u00) + t01 * bf_hi(u01) +
                     t10 * bf_hi(u10) + t11 * bf_hi(u11);

    float* op = out + (size_t)row * 16 + 2 * l;
    unsafeAtomicAdd(op,     m0);
    unsafeAtomicAdd(op + 1, m1);
}

// ---------------- Fallback (R2 kernel) if ws_size < Y_BYTES ----------------
#define FSLAB 260
__global__ __launch_bounds__(256) void basis_conv_edges(
    const float* __restrict__ x, const int* __restrict__ edge_index,
    const float* __restrict__ edge_attr, const float* __restrict__ weight,
    float* __restrict__ out)
{
    __shared__ float wl[16 * FSLAB];
    for (int idx = threadIdx.x; idx < 4096; idx += 256) {
        const int f = idx & 15, i = (idx >> 4) & 15, k = idx >> 8;
        wl[f * FSLAB + k * 16 + i] = weight[idx];
    }
    __syncthreads();
    const int f = threadIdx.x & 15, s = threadIdx.x >> 4;
    const int ebase = blockIdx.x * 256;
#pragma unroll 1
    for (int it = 0; it < 16; ++it) {
        const int e = ebase + it * 16 + s;
        const int row = edge_index[e];
        const int col = edge_index[N_EDGES + e];
        const float2 attr = ((const float2*)edge_attr)[e];
        float fu = (attr.x + 1.0f) * 1.5f;
        int iu = (int)fu; iu = iu < 0 ? 0 : (iu > 2 ? 2 : iu);
        const float wu1 = fu - (float)iu, wu0 = 1.0f - wu1;
        float fv = (attr.y + 1.0f) * 1.5f;
        int iv = (int)fv; iv = iv < 0 ? 0 : (iv > 2 ? 2 : iv);
        const float wv1 = fv - (float)iv, wv0 = 1.0f - wv1;
        const int k0 = iu * 4 + iv;
        int kb[4] = {k0, k0 + 1, k0 + 4, k0 + 5};
        float tw[4] = {wu0 * wv0, wu0 * wv1, wu1 * wv0, wu1 * wv1};
        const float4* xv = (const float4*)(x + (size_t)col * 16);
        float xs[16];
#pragma unroll
        for (int q = 0; q < 4; ++q) {
            float4 t4 = xv[q];
            xs[4*q+0]=t4.x; xs[4*q+1]=t4.y; xs[4*q+2]=t4.z; xs[4*q+3]=t4.w;
        }
        float msg = 0.0f;
#pragma unroll
        for (int p = 0; p < 4; ++p) {
            const float t = tw[p];
            const float4* wp = (const float4*)&wl[f * FSLAB + kb[p] * 16];
#pragma unroll
            for (int i4 = 0; i4 < 4; ++i4) {
                const float4 w = wp[i4];
                msg += t * (xs[4*i4+0]*w.x + xs[4*i4+1]*w.y + xs[4*i4+2]*w.z + xs[4*i4+3]*w.w);
            }
        }
        unsafeAtomicAdd(out + (size_t)row * 16 + f, msg);
    }
}

extern "C" void kernel_launch(void* const* d_in, const int* in_sizes, int n_in,
                              void* d_out, int out_size, void* d_ws, size_t ws_size,
                              hipStream_t stream) {
    const float* x  = (const float*)d_in[0];
    const int*   ei = (const int*)d_in[1];
    const float* ea = (const float*)d_in[2];
    const float* w  = (const float*)d_in[3];
    float* out = (float*)d_out;

    const int n4 = out_size / 4;
    zero_out_kernel<<<(n4 + 255) / 256, 256, 0, stream>>>((float4*)out, n4);

    if (ws_size >= Y_BYTES) {
        unsigned short* Y = (unsigned short*)d_ws;
        stage1_xw<<<4096, 256, 0, stream>>>(x, w, Y);
        // 8 threads per edge: grid = N_EDGES*8/256 = 50000 blocks
        stage2_fanout8<<<(N_EDGES * 8) / 256, 256, 0, stream>>>(ei, ea, Y, out);
    } else {
        basis_conv_edges<<<N_EDGES / 256, 256, 0, stream>>>(x, ei, ea, w, out);
    }
}

// Round 6
// 182.451 us; speedup vs baseline: 1.5160x; 1.5160x over previous
//
#include <hip/hip_runtime.h>
#include <hip/hip_fp16.h>

#define N_NODES 100000
#define N_EDGES 1600000
#define Y_ELEMS ((size_t)N_NODES * 256)       // Y[n][k][f] fp16
#define Y_BYTES (Y_ELEMS * 2)                 // 51.2 MB
#define ACC_ELEMS ((size_t)N_NODES * 16)      // f16 accumulator
#define ACC_BYTES (ACC_ELEMS * 2)             // 3.2 MB
#define WS_NEEDED (Y_BYTES + ACC_BYTES)

// ---- zero the f16 accumulator (3.2MB) ----
__global__ __launch_bounds__(256) void zero_acc_kernel(uint4* __restrict__ p, int n) {
    int i = blockIdx.x * 256 + threadIdx.x;
    if (i < n) p[i] = make_uint4(0, 0, 0, 0);
}

// ---- Stage 1: Y[n][k][f] (fp16) = sum_i x[n][i] * W[k][i][f] ----
// One wave per 64-node batch. x rows staged to LDS with COALESCED loads
// (lane = row), then per-node same-address LDS broadcast (conflict-free).
// W column (256B/lane) in registers, reused over 64 nodes.
// R4/R5 version (~44-60us) was bound by its broadcast global x loads +
// per-wave W preload amortization; this one is plain streaming.
#define XROW 20   // floats per row slab: 80B, keeps 16B align, breaks bank stride
__global__ __launch_bounds__(256) void stage1_xw_f16(
    const float* __restrict__ x,       // [N_NODES,16]
    const float* __restrict__ w,       // [16][16][16] = [k][i][f]
    unsigned short* __restrict__ Y)    // [N_NODES][16][16] fp16
{
    __shared__ float xls[4 * 64 * XROW];
    const int lane = threadIdx.x & 63;
    const int wid  = threadIdx.x >> 6;
    const int k  = lane >> 2;          // 0..15
    const int fq = lane & 3;           // 0..3
    const int batch = blockIdx.x * 4 + wid;
    const int base  = batch * 64;
    if (base >= N_NODES) return;

    float4 wr[16];
#pragma unroll
    for (int i = 0; i < 16; ++i)
        wr[i] = *(const float4*)(w + k * 256 + i * 16 + fq * 4);

    float* xl = &xls[wid * 64 * XROW];
    const int nl = base + lane;
    if (nl < N_NODES) {
        const float4* xr = (const float4*)(x + (size_t)nl * 16);
#pragma unroll
        for (int q = 0; q < 4; ++q)
            *(float4*)(xl + lane * XROW + q * 4) = xr[q];
    }
    // wave-private LDS region: compiler inserts lgkmcnt wait; no barrier needed
    __builtin_amdgcn_s_waitcnt(0);  // drain lds writes before reads (vm+lgkm)

    const int nmax = (N_NODES - base < 64) ? (N_NODES - base) : 64;
    for (int j = 0; j < nmax; ++j) {
        float xs[16];
#pragma unroll
        for (int q = 0; q < 4; ++q) {
            float4 t4 = *(const float4*)(xl + j * XROW + q * 4); // broadcast
            xs[4*q+0] = t4.x; xs[4*q+1] = t4.y; xs[4*q+2] = t4.z; xs[4*q+3] = t4.w;
        }
        float4 acc = make_float4(0.f, 0.f, 0.f, 0.f);
#pragma unroll
        for (int i = 0; i < 16; ++i) {
            acc.x += xs[i] * wr[i].x; acc.y += xs[i] * wr[i].y;
            acc.z += xs[i] * wr[i].z; acc.w += xs[i] * wr[i].w;
        }
        __half2 h0 = __floats2half2_rn(acc.x, acc.y);
        __half2 h1 = __floats2half2_rn(acc.z, acc.w);
        unsigned int u0 = *(unsigned int*)&h0;
        unsigned int u1 = *(unsigned int*)&h1;
        uint2 o = make_uint2(u0, u1);
        *(uint2*)(Y + (size_t)(base + j) * 256 + k * 16 + fq * 4) = o;
    }
}

// ---- Stage 2: 8 lanes/edge, lane l = features 2l,2l+1 ----
// Gather: 4 uint (fp16x2) loads from Y[col]; scatter: ONE pk_add_f16 atomic
// per lane -> 12.8M lane-atomics (half of R4), each instruction's lanes
// contiguous (8 lanes x 4B = dense 32B sector; R5's stride-2 half-dirty
// pattern doubled WRITE_SIZE and serialized).
__global__ __launch_bounds__(256) void stage2_pk(
    const int*   __restrict__ edge_index,  // [2, N_EDGES]
    const float* __restrict__ edge_attr,   // [N_EDGES, 2]
    const unsigned short* __restrict__ Y,  // [N_NODES][16][16] fp16
    __half2*     __restrict__ acc)         // [N_NODES][8] f16x2, pre-zeroed
{
    const int g = blockIdx.x * 256 + threadIdx.x;
    const int e = g >> 3;
    const int l = g & 7;

    const int row = edge_index[e];
    const int col = edge_index[N_EDGES + e];
    const float2 attr = ((const float2*)edge_attr)[e];

    float fu = (attr.x + 1.0f) * 1.5f;
    int iu = (int)fu; iu = iu < 0 ? 0 : (iu > 2 ? 2 : iu);
    const float wu1 = fu - (float)iu;
    const float wu0 = 1.0f - wu1;

    float fv = (attr.y + 1.0f) * 1.5f;
    int iv = (int)fv; iv = iv < 0 ? 0 : (iv > 2 ? 2 : iv);
    const float wv1 = fv - (float)iv;
    const float wv0 = 1.0f - wv1;

    const float t00 = wu0 * wv0, t01 = wu0 * wv1;
    const float t10 = wu1 * wv0, t11 = wu1 * wv1;
    const int k0 = iu * 4 + iv;

    const __half2* yb = (const __half2*)(Y + (size_t)col * 256) + l;
    const float2 f00 = __half22float2(yb[(k0)     * 8]);
    const float2 f01 = __half22float2(yb[(k0 + 1) * 8]);
    const float2 f10 = __half22float2(yb[(k0 + 4) * 8]);
    const float2 f11 = __half22float2(yb[(k0 + 5) * 8]);

    const float m0 = t00 * f00.x + t01 * f01.x + t10 * f10.x + t11 * f11.x;
    const float m1 = t00 * f00.y + t01 * f01.y + t10 * f10.y + t11 * f11.y;

    unsafeAtomicAdd(acc + (size_t)row * 8 + l, __floats2half2_rn(m0, m1));
}

// ---- Convert f16 accumulator -> fp32 d_out (overwrites everything) ----
__global__ __launch_bounds__(256) void convert_kernel(
    const __half2* __restrict__ acc, float2* __restrict__ out, int n2) {
    int i = blockIdx.x * 256 + threadIdx.x;
    if (i < n2) out[i] = __half22float2(acc[i]);
}

// ---------------- Fallback (R2, fully self-contained) ----------------
__global__ __launch_bounds__(256) void zero_out_kernel(float4* __restrict__ out, int n4) {
    int i = blockIdx.x * 256 + threadIdx.x;
    if (i < n4) out[i] = make_float4(0.f, 0.f, 0.f, 0.f);
}
#define FSLAB 260
__global__ __launch_bounds__(256) void basis_conv_edges(
    const float* __restrict__ x, const int* __restrict__ edge_index,
    const float* __restrict__ edge_attr, const float* __restrict__ weight,
    float* __restrict__ out)
{
    __shared__ float wl[16 * FSLAB];
    for (int idx = threadIdx.x; idx < 4096; idx += 256) {
        const int f = idx & 15, i = (idx >> 4) & 15, k = idx >> 8;
        wl[f * FSLAB + k * 16 + i] = weight[idx];
    }
    __syncthreads();
    const int f = threadIdx.x & 15, s = threadIdx.x >> 4;
    const int ebase = blockIdx.x * 256;
#pragma unroll 1
    for (int it = 0; it < 16; ++it) {
        const int e = ebase + it * 16 + s;
        const int row = edge_index[e];
        const int col = edge_index[N_EDGES + e];
        const float2 attr = ((const float2*)edge_attr)[e];
        float fu = (attr.x + 1.0f) * 1.5f;
        int iu = (int)fu; iu = iu < 0 ? 0 : (iu > 2 ? 2 : iu);
        const float wu1 = fu - (float)iu, wu0 = 1.0f - wu1;
        float fv = (attr.y + 1.0f) * 1.5f;
        int iv = (int)fv; iv = iv < 0 ? 0 : (iv > 2 ? 2 : iv);
        const float wv1 = fv - (float)iv, wv0 = 1.0f - wv1;
        const int k0 = iu * 4 + iv;
        int kb[4] = {k0, k0 + 1, k0 + 4, k0 + 5};
        float tw[4] = {wu0 * wv0, wu0 * wv1, wu1 * wv0, wu1 * wv1};
        const float4* xv = (const float4*)(x + (size_t)col * 16);
        float xs[16];
#pragma unroll
        for (int q = 0; q < 4; ++q) {
            float4 t4 = xv[q];
            xs[4*q+0]=t4.x; xs[4*q+1]=t4.y; xs[4*q+2]=t4.z; xs[4*q+3]=t4.w;
        }
        float msg = 0.0f;
#pragma unroll
        for (int p = 0; p < 4; ++p) {
            const float t = tw[p];
            const float4* wp = (const float4*)&wl[f * FSLAB + kb[p] * 16];
#pragma unroll
            for (int i4 = 0; i4 < 4; ++i4) {
                const float4 w = wp[i4];
                msg += t * (xs[4*i4+0]*w.x + xs[4*i4+1]*w.y + xs[4*i4+2]*w.z + xs[4*i4+3]*w.w);
            }
        }
        unsafeAtomicAdd(out + (size_t)row * 16 + f, msg);
    }
}

extern "C" void kernel_launch(void* const* d_in, const int* in_sizes, int n_in,
                              void* d_out, int out_size, void* d_ws, size_t ws_size,
                              hipStream_t stream) {
    const float* x  = (const float*)d_in[0];
    const int*   ei = (const int*)d_in[1];
    const float* ea = (const float*)d_in[2];
    const float* w  = (const float*)d_in[3];
    float* out = (float*)d_out;

    if (ws_size >= WS_NEEDED) {
        unsigned short* Y = (unsigned short*)d_ws;
        __half2* acc = (__half2*)((char*)d_ws + Y_BYTES);

        const int nacc16 = (int)(ACC_BYTES / 16);  // 200000 uint4
        zero_acc_kernel<<<(nacc16 + 255) / 256, 256, 0, stream>>>((uint4*)acc, nacc16);

        const int batches = (N_NODES + 63) / 64;   // 1563
        stage1_xw_f16<<<(batches + 3) / 4, 256, 0, stream>>>(x, w, Y);

        stage2_pk<<<(N_EDGES * 8) / 256, 256, 0, stream>>>(ei, ea, Y, acc);

        const int n2 = (int)ACC_ELEMS / 2;         // 800000 half2
        convert_kernel<<<(n2 + 255) / 256, 256, 0, stream>>>(acc, (float2*)out, n2);
    } else {
        const int n4 = out_size / 4;
        zero_out_kernel<<<(n4 + 255) / 256, 256, 0, stream>>>((float4*)out, n4);
        basis_conv_edges<<<N_EDGES / 256, 256, 0, stream>>>(x, ei, ea, w, out);
    }
}